// Round 11
// baseline (850.358 us; speedup 1.0000x reference)
//
#include <hip/hip_runtime.h>

// ---------------------------------------------------------------------------
// MultiScaleRetention forward, MI355X/gfx950.  B=1,T=4096,E=1024,VD=2048,H=8.
// R13: gemm1 occupancy fix (single variable vs R12). R10's single-pass
// out-GEMM ran 256 blocks = 1 block/CU = 1 WAVE/SIMD -> every load->barrier->
// MFMA fully latency-exposed, 32 serial K-iters. Split-K=4: 1024 blocks =
// 4 blocks/CU (4 waves/SIMD residency), 8 K-iters/block; fp32 partials to 4
// private buffers (plain coalesced stores) + k_addout4 -> d_out (each output
// element written exactly once; no atomics/memset).
// Ledger: R11 K/V frag-pack -142us GOOD; R12 XCD swizzle +4 (kept, free);
// rotary-fusion BAD; V-dbuf BAD; 1-block/CU gemm BAD.
// ---------------------------------------------------------------------------

typedef __attribute__((ext_vector_type(8)))  short  short8;
typedef __attribute__((ext_vector_type(16))) float  floatx16;

__device__ inline unsigned short f2bf(float f){
  unsigned int u = __builtin_bit_cast(unsigned int, f);
  unsigned int r = (u + 0x7fffu + ((u >> 16) & 1u)) >> 16;   // RNE
  return (unsigned short)r;
}
__device__ inline float bf2f(unsigned short u){
  unsigned int x = ((unsigned int)u) << 16;
  return __builtin_bit_cast(float, x);
}
__device__ inline void async_cp16(const void* g, const void* l){
  __builtin_amdgcn_global_load_lds((const __attribute__((address_space(1))) void*)g,
                                   (__attribute__((address_space(3))) void*)l, 16, 0, 0);
}

// ---------------- x -> bf16 -------------------------------------------------
struct us4 { unsigned short a,b,c,d; };
__global__ void k_cvt_x(const float* __restrict__ x, unsigned short* __restrict__ xb, int n4){
  int i = blockIdx.x*blockDim.x + threadIdx.x;
  if (i >= n4) return;
  float4 v = ((const float4*)x)[i];
  us4 o = { f2bf(v.x), f2bf(v.y), f2bf(v.z), f2bf(v.w) };
  ((us4*)xb)[i] = o;
}

// ---------------- fused weight transposes (fp32 RxC -> bf16 CxR) ------------
struct WPrep  { const float* src; unsigned short* dst; int R; int C; int ntile; };
struct WPrepAll { WPrep w[5]; };
__global__ __launch_bounds__(256) void k_prep_w(WPrepAll a){
  __shared__ float tile[64][65];
  int b = blockIdx.x, i = 0;
  while (b >= a.w[i].ntile){ b -= a.w[i].ntile; ++i; }
  const float* src = a.w[i].src; unsigned short* dst = a.w[i].dst;
  int R = a.w[i].R, C = a.w[i].C;
  int tpr = C >> 6;
  int c0 = (b % tpr)*64, r0 = (b / tpr)*64;
  #pragma unroll
  for (int j=0;j<16;++j){
    int idx = j*256 + threadIdx.x; int r = idx>>6, c = idx&63;
    tile[r][c] = src[(size_t)(r0+r)*C + c0 + c];
  }
  __syncthreads();
  #pragma unroll
  for (int j=0;j<16;++j){
    int idx = j*256 + threadIdx.x; int r = idx>>6, c = idx&63;
    dst[(size_t)(c0+r)*R + r0 + c] = f2bf(tile[c][r]);
  }
}

// ---------------- bf16 GEMM: C(M,N) = A(M,K) * BT(N,K)^T --------------------
// MODE 0: qkvg fanout epilogue, grid 48x32. MODE 1: fp32 store to the
// blockIdx.z partial buffer (split-K=4, summed by k_addout4). Both use the
// XCD-aware hierarchical block swizzle (bid%8 = XCD empirically).
template<int MODE>
__global__ __launch_bounds__(256) void k_gemm_bt(
    const unsigned short* __restrict__ A, const unsigned short* __restrict__ BT,
    int M, int N, int K,
    float* __restrict__ out_f32, unsigned short* __restrict__ out_v,
    unsigned short* __restrict__ out_g)
{
  __shared__ __align__(16) short As[128*64];
  __shared__ __align__(16) short Bs[128*64];
  int bx, by;
  {
    int bid = blockIdx.y*gridDim.x + blockIdx.x;   // dispatch-linear index
    int xcd = bid & 7, lo = bid >> 3;
    if (MODE==0){                                  // grid 48x32: 6 super-cols
      int st = lo >> 5, r = lo & 31;               // st 0..5, r 0..31
      bx = st*8 + (r & 7);
      by = (xcd << 2) + (r >> 3);
    } else {                                       // grid 8x32
      bx = lo & 7;
      by = (xcd << 2) + (lo >> 3);
    }
  }
  int bn = bx*128, bm = by*128;
  int tid = threadIdx.x;
  int w = tid>>6, l = tid&63;
  int wr = w>>1, wc = w&1;
  int lrow = l&31, lhi = l>>5;
  floatx16 acc[2][2];
  #pragma unroll
  for (int a=0;a<2;++a)
    #pragma unroll
    for (int b=0;b<2;++b)
      #pragma unroll
      for (int j=0;j<16;++j) acc[a][b][j]=0.f;

  int kchunk = K / gridDim.z;
  int k_beg = blockIdx.z * kchunk;
  for (int k0=k_beg; k0<k_beg+kchunk; k0+=64){
    __syncthreads();
    #pragma unroll
    for (int i=0;i<4;++i){
      int idx = i*256 + tid; int r = idx>>3, c = idx&7;
      int cs = c ^ (r&7);
      async_cp16((const char*)A  + ((size_t)(bm+r)*K + k0 + cs*8)*2, &As[idx*8]);
      async_cp16((const char*)BT + ((size_t)(bn+r)*K + k0 + cs*8)*2, &Bs[idx*8]);
    }
    __syncthreads();
    #pragma unroll
    for (int kc=0;kc<4;++kc){
      short8 af[2], bf[2];
      #pragma unroll
      for (int tm=0;tm<2;++tm){
        int row = wr*64 + tm*32 + lrow;
        int pos = (2*kc + lhi) ^ (row&7);
        af[tm] = *(const short8*)&As[row*64 + pos*8];
      }
      #pragma unroll
      for (int tn=0;tn<2;++tn){
        int row = wc*64 + tn*32 + lrow;
        int pos = (2*kc + lhi) ^ (row&7);
        bf[tn] = *(const short8*)&Bs[row*64 + pos*8];
      }
      #pragma unroll
      for (int tm=0;tm<2;++tm)
        #pragma unroll
        for (int tn=0;tn<2;++tn)
          acc[tm][tn] = __builtin_amdgcn_mfma_f32_32x32x16_bf16(af[tm], bf[tn], acc[tm][tn], 0,0,0);
    }
  }
  #pragma unroll
  for (int tm=0;tm<2;++tm)
    #pragma unroll
    for (int tn=0;tn<2;++tn)
      #pragma unroll
      for (int r=0;r<16;++r){
        int row = bm + wr*64 + tm*32 + (r&3) + 8*(r>>2) + 4*lhi;
        int col = bn + wc*64 + tn*32 + lrow;
        float v = acc[tm][tn][r];
        if (MODE==0){
          if (col < 2048)      out_f32[(size_t)row*2048 + col] = v;
          else if (col < 4096) out_v[(size_t)row*2048 + (col-2048)] = f2bf(v);
          else                 out_g[(size_t)row*2048 + (col-4096)] = f2bf(v);
        } else {
          float* dst = out_f32 + (size_t)blockIdx.z*((size_t)M*N);
          dst[(size_t)row*N + col] = v;
        }
      }
}

// ---------------- split-K=4 partial sum -> d_out ----------------------------
__global__ void k_addout4(const float* __restrict__ p, float* __restrict__ out, int n4){
  int i = blockIdx.x*blockDim.x + threadIdx.x;
  if (i >= n4) return;
  const size_t S = (size_t)4096*1024/4;          // float4 stride per partial
  float4 a = ((const float4*)p)[i];
  float4 b = ((const float4*)p)[i + S];
  float4 c = ((const float4*)p)[i + 2*S];
  float4 d = ((const float4*)p)[i + 3*S];
  float4 o = {a.x+b.x+c.x+d.x, a.y+b.y+c.y+d.y, a.z+b.z+c.z+d.z, a.w+b.w+c.w+d.w};
  ((float4*)out)[i] = o;
}

// ---------------- rotary (theta shift) + k scaling, fp32 -> bf16 ------------
// q -> qrp row-major (t,1024). k -> krP FRAGMENT-MAJOR:
// krP[((h*128 + t/32)*8 + kc)*64 + (t&31) + 32*lhi]*8 + j
// where d-within-head dd = kc*16 + lhi*8 + j. (1MB per head, 8MB total.)
__global__ void k_rotary(const float* __restrict__ qk, const float* __restrict__ sinp,
                         const float* __restrict__ cosp,
                         unsigned short* __restrict__ qrp, unsigned short* __restrict__ krP)
{
  int tid = blockIdx.x*blockDim.x + threadIdx.x;   // T*1024 pair-units
  int t = tid >> 10, p = tid & 1023;
  bool isq = p < 512;
  int c = (isq ? p : p - 512)*2;
  int d = c & 127;
  const float* base = qk + (size_t)t*2048 + (isq ? 0 : 1024) + c;
  float f0 = base[0], f1 = base[1];
  float s0 = sinp[t*128 + d],   s1 = sinp[t*128 + d + 1];
  float c0 = cosp[t*128 + d],   c1 = cosp[t*128 + d + 1];
  float r0 = f0*c0 - f1*s0;
  float r1 = f1*c1 + f0*s1;
  if (isq){
    unsigned short* dst = qrp + (size_t)t*1024 + c;
    dst[0] = f2bf(r0); dst[1] = f2bf(r1);
  } else {
    r0 *= 0.08838834764831845f; r1 *= 0.08838834764831845f;   // KD^-0.5
    int h  = c >> 7;
    int dd = c & 127;
    int kc = dd >> 4, rr = dd & 15;
    int lhi = rr >> 3, j = rr & 7;                             // c even -> j even, j+1<=7
    size_t idx = (((size_t)(h*128 + (t>>5))*8 + kc)*64 + (t&31) + 32*lhi)*8 + j;
    krP[idx]   = f2bf(r0);
    krP[idx+1] = f2bf(r1);
  }
}

// ---------------- V transpose + fragment-major pack -------------------------
// v_bf (t,2048) -> vP[(((h*2+hh)*128 + s/32)*8 + nt*2+kc)*64 + lrow+32*lhi]*8+j
// where col c = h*256+hh*128+nt*32+lrow, s%32 = kc*16+lhi*8+j. 16MB total.
__global__ __launch_bounds__(256) void k_transpose_pack(const unsigned short* __restrict__ src,
    unsigned short* __restrict__ vP){
  __shared__ unsigned short tile[64][72];
  int c0 = blockIdx.x*64, r0 = blockIdx.y*64;    // c over 2048, r=s over 4096
  #pragma unroll
  for (int i=0;i<16;++i){
    int idx = i*256 + threadIdx.x; int r = idx>>6, c = idx&63;
    tile[r][c] = src[(size_t)(r0+r)*2048 + c0 + c];
  }
  __syncthreads();
  #pragma unroll
  for (int it=0; it<2; ++it){
    int idx = it*256 + threadIdx.x;
    int cc = idx & 63, so = idx >> 6;            // so = s-octet 0..7
    int C = c0 + cc;
    int s = r0 + so*8;
    int h = C>>8, hh = (C>>7)&1, nt = (C>>5)&3, lrow = C&31;
    int ts = s>>5, s32 = s&31, kc = s32>>4, lhi = (s32>>3)&1;
    size_t dst8 = ((size_t)((h*2+hh)*128 + ts)*8 + nt*2+kc)*64 + lrow + 32*lhi;
    short8 v;
    #pragma unroll
    for (int k=0;k<8;++k) v[k] = (short)tile[so*8+k][cc];
    *(short8*)(vP + dst8*8) = v;
  }
}

// ---------------- retention attention (LDS-free, swapped-QK, coalesced) -----
// 2048 blocks: gid&7 = head, gid>>3 = [qt desc]x[chunk4]. 4 waves/block =
// (qhalf x hdhalf); wave = 32 q-rows x 128 hd. s-range split into 4 chunks
// (max 32 tiles/wave); bf16 partial O + fp32 partial den per chunk;
// k_rmsgate combines. QK^T SWAPPED (dual 4-deep chains); P -> PV A-fragment
// in-register (cvt_pk + permlane32_swap). K/V fragments read from the
// FRAGMENT-MAJOR packed buffers: every load instruction = 64 lanes x 16B
// contiguous (fully coalesced; hh pairs hit identical K addresses in L1).
// Per tile: LOADV(cur); LOADK(next); sched_barrier(0); COMPUTE(cur).
__global__ __launch_bounds__(256, 2) void k_attn(
    const unsigned short* __restrict__ qr, const unsigned short* __restrict__ krP,
    const unsigned short* __restrict__ vP,
    unsigned short* __restrict__ o_parts, float* __restrict__ den_g)
{
  int gid = blockIdx.x;
  int head = gid & 7;
  int rest = gid >> 3;                           // 0..255
  int qt = 63 - (rest >> 2);                     // longest blocks first
  int chunk = rest & 3;
  int tid = threadIdx.x;
  int w = tid>>6, l = tid&63;
  int qh = w>>1, hh = w&1;
  int lrow = l&31, lhi = l>>5;
  int tbase = qt*64 + qh*32;                     // wave's first q-row

  float gamma = 1.f - exp2f(-5.f - (float)head);
  float L = log2f(gamma);                        // negative

  int dmax = (int)(40.0f/(-L));                  // decay < 2^-40 beyond: skip
  int s_start = tbase - dmax; if (s_start < 0) s_start = 0; s_start &= ~31;
  int N = ((tbase - s_start) >> 5) + 1;          // number of 32-col s-tiles
  int q4 = (N+3)>>2;                             // tiles per chunk (ceil)
  int t0 = chunk*q4;
  int t1 = t0 + q4; if (t1 > N) t1 = N;

  floatx16 o[4];
  #pragma unroll
  for (int i=0;i<4;++i)
    #pragma unroll
    for (int j=0;j<16;++j) o[i][j]=0.f;
  float den_ = 0.f;

  if (t0 < t1){
    int sb = s_start + t0*32;
    int se = s_start + (t1-1)*32;                // last tile start

    short8 qf[8];                                // B-operand: lane&31 = q-col
    const unsigned short* qbase = qr + (size_t)(tbase+lrow)*1024 + head*128 + lhi*8;
    #pragma unroll
    for (int kc=0;kc<8;++kc) qf[kc] = *(const short8*)(qbase + kc*16);

    // decay = 2^(L*(qglob - sglob)), qglob=tbase+lrow, sglob=s0+srow(r),
    // srow=(r&3)+8*(r>>2)+4*lhi.
    float lanefac = exp2f(L*((float)lrow - 4.0f*(float)lhi));
    float e1[4], e2[4];
    #pragma unroll
    for (int i=0;i<4;++i){ e1[i] = exp2f(-L*(float)i); e2[i] = exp2f(-L*8.0f*(float)i); }

    // packed bases: per-tile stride 4096 elems (8KB); l*8 = lane slot
    const unsigned short* kbP = krP + (size_t)head*128*4096 + l*8;
    const unsigned short* vbP = vP  + (size_t)(head*2+hh)*128*4096 + l*8;

#define LOADK(S0, KF) do{ \
    const unsigned short* kp_ = kbP + (size_t)((S0)>>5)*4096; \
    _Pragma("unroll") \
    for (int kc=0;kc<8;++kc) KF[kc] = *(const short8*)(kp_ + kc*512); \
  }while(0)

#define LOADV(S0, VF) do{ \
    const unsigned short* vp_ = vbP + (size_t)((S0)>>5)*4096; \
    _Pragma("unroll") \
    for (int f=0;f<8;++f) VF[f] = *(const short8*)(vp_ + f*512); \
  }while(0)

#define COMPUTE(S0, KF, VF) do{ \
    floatx16 sa_, sb_; \
    _Pragma("unroll") for (int j=0;j<16;++j){ sa_[j]=0.f; sb_[j]=0.f; } \
    __builtin_amdgcn_s_setprio(1); \
    _Pragma("unroll") \
    for (int kc=0;kc<4;++kc){ \
      sa_ = __builtin_amdgcn_mfma_f32_32x32x16_bf16(KF[kc],   qf[kc],   sa_, 0,0,0); \
      sb_ = __builtin_amdgcn_mfma_f32_32x32x16_bf16(KF[kc+4], qf[kc+4], sb_, 0,0,0); \
    } \
    __builtin_amdgcn_s_setprio(0); \
    float tf_ = exp2f(L*(float)(tbase - (S0))) * lanefac; \
    bool diag_ = ((S0) == tbase); \
    float pv_[16]; \
    _Pragma("unroll") \
    for (int r=0;r<16;++r){ \
      float val_ = (sa_[r]+sb_[r])*(tf_*e1[r&3]*e2[r>>2]); \
      if (diag_){ if (lrow < (r&3)+8*(r>>2)+4*lhi) val_ = 0.f; } \
      den_ += fabsf(val_); \
      pv_[r] = val_; \
    } \
    unsigned int w0_,w1_,w2_,w3_,w4_,w5_,w6_,w7_; \
    asm("v_cvt_pk_bf16_f32 %0, %1, %2" : "=v"(w0_) : "v"(pv_[0]),  "v"(pv_[1])); \
    asm("v_cvt_pk_bf16_f32 %0, %1, %2" : "=v"(w1_) : "v"(pv_[2]),  "v"(pv_[3])); \
    asm("v_cvt_pk_bf16_f32 %0, %1, %2" : "=v"(w2_) : "v"(pv_[4]),  "v"(pv_[5])); \
    asm("v_cvt_pk_bf16_f32 %0, %1, %2" : "=v"(w3_) : "v"(pv_[6]),  "v"(pv_[7])); \
    asm("v_cvt_pk_bf16_f32 %0, %1, %2" : "=v"(w4_) : "v"(pv_[8]),  "v"(pv_[9])); \
    asm("v_cvt_pk_bf16_f32 %0, %1, %2" : "=v"(w5_) : "v"(pv_[10]), "v"(pv_[11])); \
    asm("v_cvt_pk_bf16_f32 %0, %1, %2" : "=v"(w6_) : "v"(pv_[12]), "v"(pv_[13])); \
    asm("v_cvt_pk_bf16_f32 %0, %1, %2" : "=v"(w7_) : "v"(pv_[14]), "v"(pv_[15])); \
    asm("v_permlane32_swap_b32 %0, %1" : "+v"(w0_), "+v"(w2_)); \
    asm("v_permlane32_swap_b32 %0, %1" : "+v"(w1_), "+v"(w3_)); \
    asm("v_permlane32_swap_b32 %0, %1" : "+v"(w4_), "+v"(w6_)); \
    asm("v_permlane32_swap_b32 %0, %1" : "+v"(w5_), "+v"(w7_)); \
    union { unsigned int u[4]; short8 s; } pa0_, pa1_; \
    pa0_.u[0]=w0_; pa0_.u[1]=w1_; pa0_.u[2]=w2_; pa0_.u[3]=w3_; \
    pa1_.u[0]=w4_; pa1_.u[1]=w5_; pa1_.u[2]=w6_; pa1_.u[3]=w7_; \
    __builtin_amdgcn_s_setprio(1); \
    _Pragma("unroll") \
    for (int nt=0;nt<4;++nt){ \
      o[nt] = __builtin_amdgcn_mfma_f32_32x32x16_bf16(pa0_.s, VF[nt*2+0], o[nt], 0,0,0); \
      o[nt] = __builtin_amdgcn_mfma_f32_32x32x16_bf16(pa1_.s, VF[nt*2+1], o[nt], 0,0,0); \
    } \
    __builtin_amdgcn_s_setprio(0); \
  }while(0)

    short8 kfA[8], kfB[8];
    LOADK(sb, kfA);
    for (int s0 = sb;; s0 += 64){
      {
        short8 vfA[8];
        LOADV(s0, vfA);                          // V first (older in vmcnt order)
        if (s0 + 32 <= se) LOADK(s0+32, kfB);    // K one tile ahead
        __builtin_amdgcn_sched_barrier(0);       // pin: loads issued before MFMAs
        COMPUTE(s0, kfA, vfA);
      }
      if (s0 + 32 > se) break;
      {
        short8 vfB[8];
        LOADV(s0+32, vfB);
        if (s0 + 64 <= se) LOADK(s0+64, kfA);
        __builtin_amdgcn_sched_barrier(0);
        COMPUTE(s0+32, kfB, vfB);
      }
      if (s0 + 64 > se) break;
    }
#undef LOADK
#undef LOADV
#undef COMPUTE
  }

  // partial den: per-lane scalar; q-row l&31 total = own + partner half.
  // hh waves compute identical den; only hh==0 stores. Unique writer per
  // (chunk,row,head) -> no atomics.
  if (hh == 0){
    float d = den_ + __shfl_xor(den_, 32, 64);
    if (lhi == 0)
      den_g[((size_t)chunk*4096 + tbase + lrow)*8 + head] = d;
  }

  // partial O: bf16 store to the chunk-private quarter (zeros if empty chunk).
  unsigned short* ob = o_parts + (size_t)chunk*4096*2048;
  #pragma unroll
  for (int nt=0;nt<4;++nt)
    #pragma unroll
    for (int r=0;r<16;++r){
      int row = (r&3)+8*(r>>2)+4*lhi;
      ob[(size_t)(tbase+row)*2048 + head*256 + hh*128 + nt*32 + lrow] = f2bf(o[nt][r]);
    }
}

// ---------------- partial-sum + den-normalize + group RMS + SiLU gate -------
__global__ __launch_bounds__(256) void k_rmsgate(const unsigned short* __restrict__ o_parts,
    const unsigned short* __restrict__ g_bf, const float* __restrict__ den_g,
    unsigned short* __restrict__ gated)
{
  int t = blockIdx.x;
  int tid = threadIdx.x;
  int head = tid >> 5;                       // 32 threads = one head group (256)
  float den = den_g[(size_t)t*8 + head]
            + den_g[(size_t)( 4096 + t)*8 + head]
            + den_g[(size_t)( 8192 + t)*8 + head]
            + den_g[(size_t)(12288 + t)*8 + head];
  float rs  = 1.0f/fminf(fmaxf(den, 1.0f), 50000.0f);
  size_t base = (size_t)t*2048 + tid*8;
  const size_t CS = (size_t)4096*2048;
  short8 a0 = *(const short8*)(o_parts + base);
  short8 a1 = *(const short8*)(o_parts + CS + base);
  short8 a2 = *(const short8*)(o_parts + 2*CS + base);
  short8 a3 = *(const short8*)(o_parts + 3*CS + base);
  short8 gv = *(const short8*)(g_bf + base);
  float of[8]; float ss = 0.f;
  #pragma unroll
  for (int j=0;j<8;++j){
    of[j] = (bf2f((unsigned short)a0[j]) + bf2f((unsigned short)a1[j])
           + bf2f((unsigned short)a2[j]) + bf2f((unsigned short)a3[j])) * rs;
    ss += of[j]*of[j];
  }
  #pragma unroll
  for (int off=1; off<32; off<<=1) ss += __shfl_xor(ss, off, 64);
  float rms = rsqrtf(ss*(1.0f/256.0f) + 1e-6f);
  short8 outv;
  #pragma unroll
  for (int j=0;j<8;++j){
    float g = bf2f((unsigned short)gv[j]);
    float si = g / (1.0f + expf(-g));
    outv[j] = (short)f2bf(si * of[j] * rms);
  }
  *(short8*)(gated + base) = outv;
}

// ---------------------------------------------------------------------------
extern "C" void kernel_launch(void* const* d_in, const int* in_sizes, int n_in,
                              void* d_out, int out_size, void* d_ws, size_t ws_size,
                              hipStream_t stream)
{
  const float* x    = (const float*)d_in[0];
  const float* sinp = (const float*)d_in[1];
  const float* cosp = (const float*)d_in[2];
  // d_in[3] = inner_mask: intentionally unused (computed analytically)
  const float* Wq = (const float*)d_in[4];
  const float* Wk = (const float*)d_in[5];
  const float* Wv = (const float*)d_in[6];
  const float* Wg = (const float*)d_in[7];
  const float* Wo = (const float*)d_in[8];

  char* ws = (char*)d_ws;
  size_t off = 0;
  auto alloc = [&](size_t bytes)->char*{ char* p = ws + off; off += (bytes + 255) & ~(size_t)255; return p; };
  unsigned short* x_bf   = (unsigned short*)alloc((size_t)4096*1024*2);  // reused as qr, then gated head
  unsigned short* WallT  = (unsigned short*)alloc((size_t)6144*1024*2);  // reused as krP, then gated tail
  float*          qk_f32 = (float*)         alloc((size_t)4096*2048*4);
  unsigned short* v_bf   = (unsigned short*)alloc((size_t)4096*2048*2);
  unsigned short* g_bf   = (unsigned short*)alloc((size_t)4096*2048*2);
  unsigned short* vP     = (unsigned short*)alloc((size_t)2048*4096*2);  // packed V fragments
  unsigned short* WoT    = (unsigned short*)alloc((size_t)1024*2048*2);
  unsigned short* o_parts= (unsigned short*)alloc((size_t)4*4096*2048*2); // 4 bf16 chunk partials
  float*          den_g  = (float*)         alloc((size_t)4*4096*8*4);
  float*          p_out4 = (float*)         alloc((size_t)4*4096*1024*4); // split-K=4 fp32 partials
  unsigned short* qrp    = x_bf;                       // alias (x_bf dead after qkvg GEMM)
  unsigned short* krP    = WallT;                      // alias (WallT dead after qkvg GEMM)
  unsigned short* gated  = x_bf;                       // alias (qr/krP dead after k_attn)

  // prep
  k_cvt_x<<<4096, 256, 0, stream>>>(x, x_bf, 4096*1024/4);
  WPrepAll pa;
  pa.w[0] = { Wq, WallT,                        1024, 1024, 256 };
  pa.w[1] = { Wk, WallT + 1024*1024,            1024, 1024, 256 };
  pa.w[2] = { Wv, WallT + 2048*1024,            1024, 2048, 512 };
  pa.w[3] = { Wg, WallT + (size_t)4096*1024,    1024, 2048, 512 };
  pa.w[4] = { Wo, WoT,                          2048, 1024, 512 };
  k_prep_w<<<2048, 256, 0, stream>>>(pa);

  // qkvg = x @ [Wq|Wk|Wv|Wg]
  k_gemm_bt<0><<<dim3(48,32,1), 256, 0, stream>>>(x_bf, WallT, 4096, 6144, 1024, qk_f32, v_bf, g_bf);

  // rotary + k-scaling; q -> qrp row-major, k -> krP fragment-major
  k_rotary<<<16384, 256, 0, stream>>>(qk_f32, sinp, cosp, qrp, krP);

  // V transpose + fragment-major pack
  k_transpose_pack<<<dim3(32,64), 256, 0, stream>>>(v_bf, vP);

  // retention attention -> 4 chunk-private bf16 partial O + fp32 partial den
  k_attn<<<2048, 256, 0, stream>>>(qrp, krP, vP, o_parts, den_g);

  // partial-sum + den-clip divide + RMS(group=256) + silu(g) gate -> gated
  k_rmsgate<<<4096, 256, 0, stream>>>(o_parts, g_bf, den_g, gated);

  // out = gated @ Wo -> split-K=4 fp32 partials (4 blocks/CU), then sum
  k_gemm_bt<1><<<dim3(8,32,4), 256, 0, stream>>>(gated, WoT, 4096, 1024, 2048,
                                                 p_out4, nullptr, nullptr);
  k_addout4<<<4096, 256, 0, stream>>>(p_out4, (float*)d_out, 4096*1024/4);

  (void)in_sizes; (void)n_in; (void)out_size; (void)ws_size;
}

// Round 12
// 837.011 us; speedup vs baseline: 1.0159x; 1.0159x over previous
//
#include <hip/hip_runtime.h>

// ---------------------------------------------------------------------------
// MultiScaleRetention forward, MI355X/gfx950.  B=1,T=4096,E=1024,VD=2048,H=8.
// R14: recover + trim. (1) gemm1 reverted to R12 single-pass direct d_out
// (R13's split-K=4 was +9: gemm1 measured insensitive across K-split 1/2/4).
// (2) cvt_x+prep_w merged into k_prep; rotary+pack merged into k_rotpack
// (fewer launch gaps; identical math). attn/gemm0 untouched for clean
// attribution. Budget model: rest~390us stable across 13 rounds; ~150us of
// it attributed to harness restore-memsets (uncontrollable); controllable =
// attn ~110 + gemm0 ~80 + gemm1 ~40 + elementwise ~45.
// Ledger: R11 K/V frag-pack -142 GOOD; R12 XCD swizzle ~0 (kept, free);
// splitK4 gemm1 BAD (+9); rotary-fusion BAD; V-dbuf BAD; 1-blk/CU gemm ok.
// ---------------------------------------------------------------------------

typedef __attribute__((ext_vector_type(8)))  short  short8;
typedef __attribute__((ext_vector_type(16))) float  floatx16;

__device__ inline unsigned short f2bf(float f){
  unsigned int u = __builtin_bit_cast(unsigned int, f);
  unsigned int r = (u + 0x7fffu + ((u >> 16) & 1u)) >> 16;   // RNE
  return (unsigned short)r;
}
__device__ inline float bf2f(unsigned short u){
  unsigned int x = ((unsigned int)u) << 16;
  return __builtin_bit_cast(float, x);
}
__device__ inline void async_cp16(const void* g, const void* l){
  __builtin_amdgcn_global_load_lds((const __attribute__((address_space(1))) void*)g,
                                   (__attribute__((address_space(3))) void*)l, 16, 0, 0);
}

// ---------------- merged: x->bf16 cvt  +  weight transposes ------------------
struct us4 { unsigned short a,b,c,d; };
struct WPrep  { const float* src; unsigned short* dst; int R; int C; int ntile; };
struct WPrepAll { WPrep w[5]; };
// grid 6144: blocks [0,4096) = cvt x (fp32->bf16, 1024 elems/block);
// blocks [4096,6144) = fp32 RxC -> bf16 CxR weight transpose tiles.
__global__ __launch_bounds__(256) void k_prep(const float* __restrict__ x,
    unsigned short* __restrict__ xb, WPrepAll a){
  __shared__ float tile[64][65];
  int blk = blockIdx.x;
  if (blk < 4096){
    int i = blk*256 + threadIdx.x;
    float4 v = ((const float4*)x)[i];
    us4 o = { f2bf(v.x), f2bf(v.y), f2bf(v.z), f2bf(v.w) };
    ((us4*)xb)[i] = o;
    return;
  }
  int b = blk - 4096, i = 0;
  while (b >= a.w[i].ntile){ b -= a.w[i].ntile; ++i; }
  const float* src = a.w[i].src; unsigned short* dst = a.w[i].dst;
  int R = a.w[i].R, C = a.w[i].C;
  int tpr = C >> 6;
  int c0 = (b % tpr)*64, r0 = (b / tpr)*64;
  #pragma unroll
  for (int j=0;j<16;++j){
    int idx = j*256 + threadIdx.x; int r = idx>>6, c = idx&63;
    tile[r][c] = src[(size_t)(r0+r)*C + c0 + c];
  }
  __syncthreads();
  #pragma unroll
  for (int j=0;j<16;++j){
    int idx = j*256 + threadIdx.x; int r = idx>>6, c = idx&63;
    dst[(size_t)(c0+r)*R + r0 + c] = f2bf(tile[c][r]);
  }
}

// ---------------- bf16 GEMM: C(M,N) = A(M,K) * BT(N,K)^T --------------------
// MODE 0: qkvg fanout epilogue, grid 48x32. MODE 1: plain fp32 store to
// d_out (grid 8x32, z=1: one write per element overwrites poison). Both use
// the XCD-aware hierarchical block swizzle (bid%8 = XCD empirically).
template<int MODE>
__global__ __launch_bounds__(256) void k_gemm_bt(
    const unsigned short* __restrict__ A, const unsigned short* __restrict__ BT,
    int M, int N, int K,
    float* __restrict__ out_f32, unsigned short* __restrict__ out_v,
    unsigned short* __restrict__ out_g)
{
  __shared__ __align__(16) short As[128*64];
  __shared__ __align__(16) short Bs[128*64];
  int bx, by;
  {
    int bid = blockIdx.y*gridDim.x + blockIdx.x;   // dispatch-linear index
    int xcd = bid & 7, lo = bid >> 3;
    if (MODE==0){                                  // grid 48x32: 6 super-cols
      int st = lo >> 5, r = lo & 31;               // st 0..5, r 0..31
      bx = st*8 + (r & 7);
      by = (xcd << 2) + (r >> 3);
    } else {                                       // grid 8x32
      bx = lo & 7;
      by = (xcd << 2) + (lo >> 3);
    }
  }
  int bn = bx*128, bm = by*128;
  int tid = threadIdx.x;
  int w = tid>>6, l = tid&63;
  int wr = w>>1, wc = w&1;
  int lrow = l&31, lhi = l>>5;
  floatx16 acc[2][2];
  #pragma unroll
  for (int a=0;a<2;++a)
    #pragma unroll
    for (int b=0;b<2;++b)
      #pragma unroll
      for (int j=0;j<16;++j) acc[a][b][j]=0.f;

  for (int k0=0; k0<K; k0+=64){
    __syncthreads();
    #pragma unroll
    for (int i=0;i<4;++i){
      int idx = i*256 + tid; int r = idx>>3, c = idx&7;
      int cs = c ^ (r&7);
      async_cp16((const char*)A  + ((size_t)(bm+r)*K + k0 + cs*8)*2, &As[idx*8]);
      async_cp16((const char*)BT + ((size_t)(bn+r)*K + k0 + cs*8)*2, &Bs[idx*8]);
    }
    __syncthreads();
    #pragma unroll
    for (int kc=0;kc<4;++kc){
      short8 af[2], bf[2];
      #pragma unroll
      for (int tm=0;tm<2;++tm){
        int row = wr*64 + tm*32 + lrow;
        int pos = (2*kc + lhi) ^ (row&7);
        af[tm] = *(const short8*)&As[row*64 + pos*8];
      }
      #pragma unroll
      for (int tn=0;tn<2;++tn){
        int row = wc*64 + tn*32 + lrow;
        int pos = (2*kc + lhi) ^ (row&7);
        bf[tn] = *(const short8*)&Bs[row*64 + pos*8];
      }
      #pragma unroll
      for (int tm=0;tm<2;++tm)
        #pragma unroll
        for (int tn=0;tn<2;++tn)
          acc[tm][tn] = __builtin_amdgcn_mfma_f32_32x32x16_bf16(af[tm], bf[tn], acc[tm][tn], 0,0,0);
    }
  }
  #pragma unroll
  for (int tm=0;tm<2;++tm)
    #pragma unroll
    for (int tn=0;tn<2;++tn)
      #pragma unroll
      for (int r=0;r<16;++r){
        int row = bm + wr*64 + tm*32 + (r&3) + 8*(r>>2) + 4*lhi;
        int col = bn + wc*64 + tn*32 + lrow;
        float v = acc[tm][tn][r];
        if (MODE==0){
          if (col < 2048)      out_f32[(size_t)row*2048 + col] = v;
          else if (col < 4096) out_v[(size_t)row*2048 + (col-2048)] = f2bf(v);
          else                 out_g[(size_t)row*2048 + (col-4096)] = f2bf(v);
        } else {
          out_f32[(size_t)row*N + col] = v;
        }
      }
}

// ---------------- merged: rotary(+k-scale)  +  V transpose/pack -------------
// grid 18432: blocks [0,16384) = rotary: q -> qrp row-major; k -> krP
// fragment-major krP[((h*128+t/32)*8+kc)*64 + (t&31)+32*lhi]*8 + j,
// dd = kc*16+lhi*8+j. Blocks [16384,18432) = V transpose+pack:
// v_bf(t,2048) -> vP[(((h*2+hh)*128 + s/32)*8 + nt*2+kc)*64 + lrow+32*lhi]*8+j.
__global__ __launch_bounds__(256) void k_rotpack(const float* __restrict__ qk,
    const float* __restrict__ sinp, const float* __restrict__ cosp,
    unsigned short* __restrict__ qrp, unsigned short* __restrict__ krP,
    const unsigned short* __restrict__ vsrc, unsigned short* __restrict__ vP)
{
  __shared__ unsigned short tile[64][72];
  int blk = blockIdx.x;
  if (blk < 16384){
    int tid = blk*256 + threadIdx.x;               // T*1024 pair-units
    int t = tid >> 10, p = tid & 1023;
    bool isq = p < 512;
    int c = (isq ? p : p - 512)*2;
    int d = c & 127;
    const float* base = qk + (size_t)t*2048 + (isq ? 0 : 1024) + c;
    float f0 = base[0], f1 = base[1];
    float s0 = sinp[t*128 + d],   s1 = sinp[t*128 + d + 1];
    float c0 = cosp[t*128 + d],   c1 = cosp[t*128 + d + 1];
    float r0 = f0*c0 - f1*s0;
    float r1 = f1*c1 + f0*s1;
    if (isq){
      unsigned short* dst = qrp + (size_t)t*1024 + c;
      dst[0] = f2bf(r0); dst[1] = f2bf(r1);
    } else {
      r0 *= 0.08838834764831845f; r1 *= 0.08838834764831845f;   // KD^-0.5
      int h  = c >> 7;
      int dd = c & 127;
      int kc = dd >> 4, rr = dd & 15;
      int lhi = rr >> 3, j = rr & 7;               // c even -> j even, j+1<=7
      size_t idx = (((size_t)(h*128 + (t>>5))*8 + kc)*64 + (t&31) + 32*lhi)*8 + j;
      krP[idx]   = f2bf(r0);
      krP[idx+1] = f2bf(r1);
    }
    return;
  }
  int bb = blk - 16384;                            // 0..2047
  int c0 = (bb & 31)*64, r0 = (bb >> 5)*64;        // c over 2048, r=s over 4096
  #pragma unroll
  for (int i=0;i<16;++i){
    int idx = i*256 + threadIdx.x; int r = idx>>6, c = idx&63;
    tile[r][c] = vsrc[(size_t)(r0+r)*2048 + c0 + c];
  }
  __syncthreads();
  #pragma unroll
  for (int it=0; it<2; ++it){
    int idx = it*256 + threadIdx.x;
    int cc = idx & 63, so = idx >> 6;              // so = s-octet 0..7
    int C = c0 + cc;
    int s = r0 + so*8;
    int h = C>>8, hh = (C>>7)&1, nt = (C>>5)&3, lrow = C&31;
    int ts = s>>5, s32 = s&31, kc = s32>>4, lhi = (s32>>3)&1;
    size_t dst8 = ((size_t)((h*2+hh)*128 + ts)*8 + nt*2+kc)*64 + lrow + 32*lhi;
    short8 v;
    #pragma unroll
    for (int k=0;k<8;++k) v[k] = (short)tile[so*8+k][cc];
    *(short8*)(vP + dst8*8) = v;
  }
}

// ---------------- retention attention (LDS-free, swapped-QK, coalesced) -----
// 2048 blocks: gid&7 = head, gid>>3 = [qt desc]x[chunk4]. 4 waves/block =
// (qhalf x hdhalf); wave = 32 q-rows x 128 hd. s-range split into 4 chunks
// (max 32 tiles/wave); bf16 partial O + fp32 partial den per chunk;
// k_rmsgate combines. QK^T SWAPPED (dual 4-deep chains); P -> PV A-fragment
// in-register (cvt_pk + permlane32_swap). K/V fragments read from the
// FRAGMENT-MAJOR packed buffers: every load instruction = 64 lanes x 16B
// contiguous (fully coalesced; hh pairs hit identical K addresses in L1).
// Per tile: LOADV(cur); LOADK(next); sched_barrier(0); COMPUTE(cur).
__global__ __launch_bounds__(256, 2) void k_attn(
    const unsigned short* __restrict__ qr, const unsigned short* __restrict__ krP,
    const unsigned short* __restrict__ vP,
    unsigned short* __restrict__ o_parts, float* __restrict__ den_g)
{
  int gid = blockIdx.x;
  int head = gid & 7;
  int rest = gid >> 3;                           // 0..255
  int qt = 63 - (rest >> 2);                     // longest blocks first
  int chunk = rest & 3;
  int tid = threadIdx.x;
  int w = tid>>6, l = tid&63;
  int qh = w>>1, hh = w&1;
  int lrow = l&31, lhi = l>>5;
  int tbase = qt*64 + qh*32;                     // wave's first q-row

  float gamma = 1.f - exp2f(-5.f - (float)head);
  float L = log2f(gamma);                        // negative

  int dmax = (int)(40.0f/(-L));                  // decay < 2^-40 beyond: skip
  int s_start = tbase - dmax; if (s_start < 0) s_start = 0; s_start &= ~31;
  int N = ((tbase - s_start) >> 5) + 1;          // number of 32-col s-tiles
  int q4 = (N+3)>>2;                             // tiles per chunk (ceil)
  int t0 = chunk*q4;
  int t1 = t0 + q4; if (t1 > N) t1 = N;

  floatx16 o[4];
  #pragma unroll
  for (int i=0;i<4;++i)
    #pragma unroll
    for (int j=0;j<16;++j) o[i][j]=0.f;
  float den_ = 0.f;

  if (t0 < t1){
    int sb = s_start + t0*32;
    int se = s_start + (t1-1)*32;                // last tile start

    short8 qf[8];                                // B-operand: lane&31 = q-col
    const unsigned short* qbase = qr + (size_t)(tbase+lrow)*1024 + head*128 + lhi*8;
    #pragma unroll
    for (int kc=0;kc<8;++kc) qf[kc] = *(const short8*)(qbase + kc*16);

    // decay = 2^(L*(qglob - sglob)), qglob=tbase+lrow, sglob=s0+srow(r),
    // srow=(r&3)+8*(r>>2)+4*lhi.
    float lanefac = exp2f(L*((float)lrow - 4.0f*(float)lhi));
    float e1[4], e2[4];
    #pragma unroll
    for (int i=0;i<4;++i){ e1[i] = exp2f(-L*(float)i); e2[i] = exp2f(-L*8.0f*(float)i); }

    // packed bases: per-tile stride 4096 elems (8KB); l*8 = lane slot
    const unsigned short* kbP = krP + (size_t)head*128*4096 + l*8;
    const unsigned short* vbP = vP  + (size_t)(head*2+hh)*128*4096 + l*8;

#define LOADK(S0, KF) do{ \
    const unsigned short* kp_ = kbP + (size_t)((S0)>>5)*4096; \
    _Pragma("unroll") \
    for (int kc=0;kc<8;++kc) KF[kc] = *(const short8*)(kp_ + kc*512); \
  }while(0)

#define LOADV(S0, VF) do{ \
    const unsigned short* vp_ = vbP + (size_t)((S0)>>5)*4096; \
    _Pragma("unroll") \
    for (int f=0;f<8;++f) VF[f] = *(const short8*)(vp_ + f*512); \
  }while(0)

#define COMPUTE(S0, KF, VF) do{ \
    floatx16 sa_, sb_; \
    _Pragma("unroll") for (int j=0;j<16;++j){ sa_[j]=0.f; sb_[j]=0.f; } \
    __builtin_amdgcn_s_setprio(1); \
    _Pragma("unroll") \
    for (int kc=0;kc<4;++kc){ \
      sa_ = __builtin_amdgcn_mfma_f32_32x32x16_bf16(KF[kc],   qf[kc],   sa_, 0,0,0); \
      sb_ = __builtin_amdgcn_mfma_f32_32x32x16_bf16(KF[kc+4], qf[kc+4], sb_, 0,0,0); \
    } \
    __builtin_amdgcn_s_setprio(0); \
    float tf_ = exp2f(L*(float)(tbase - (S0))) * lanefac; \
    bool diag_ = ((S0) == tbase); \
    float pv_[16]; \
    _Pragma("unroll") \
    for (int r=0;r<16;++r){ \
      float val_ = (sa_[r]+sb_[r])*(tf_*e1[r&3]*e2[r>>2]); \
      if (diag_){ if (lrow < (r&3)+8*(r>>2)+4*lhi) val_ = 0.f; } \
      den_ += fabsf(val_); \
      pv_[r] = val_; \
    } \
    unsigned int w0_,w1_,w2_,w3_,w4_,w5_,w6_,w7_; \
    asm("v_cvt_pk_bf16_f32 %0, %1, %2" : "=v"(w0_) : "v"(pv_[0]),  "v"(pv_[1])); \
    asm("v_cvt_pk_bf16_f32 %0, %1, %2" : "=v"(w1_) : "v"(pv_[2]),  "v"(pv_[3])); \
    asm("v_cvt_pk_bf16_f32 %0, %1, %2" : "=v"(w2_) : "v"(pv_[4]),  "v"(pv_[5])); \
    asm("v_cvt_pk_bf16_f32 %0, %1, %2" : "=v"(w3_) : "v"(pv_[6]),  "v"(pv_[7])); \
    asm("v_cvt_pk_bf16_f32 %0, %1, %2" : "=v"(w4_) : "v"(pv_[8]),  "v"(pv_[9])); \
    asm("v_cvt_pk_bf16_f32 %0, %1, %2" : "=v"(w5_) : "v"(pv_[10]), "v"(pv_[11])); \
    asm("v_cvt_pk_bf16_f32 %0, %1, %2" : "=v"(w6_) : "v"(pv_[12]), "v"(pv_[13])); \
    asm("v_cvt_pk_bf16_f32 %0, %1, %2" : "=v"(w7_) : "v"(pv_[14]), "v"(pv_[15])); \
    asm("v_permlane32_swap_b32 %0, %1" : "+v"(w0_), "+v"(w2_)); \
    asm("v_permlane32_swap_b32 %0, %1" : "+v"(w1_), "+v"(w3_)); \
    asm("v_permlane32_swap_b32 %0, %1" : "+v"(w4_), "+v"(w6_)); \
    asm("v_permlane32_swap_b32 %0, %1" : "+v"(w5_), "+v"(w7_)); \
    union { unsigned int u[4]; short8 s; } pa0_, pa1_; \
    pa0_.u[0]=w0_; pa0_.u[1]=w1_; pa0_.u[2]=w2_; pa0_.u[3]=w3_; \
    pa1_.u[0]=w4_; pa1_.u[1]=w5_; pa1_.u[2]=w6_; pa1_.u[3]=w7_; \
    __builtin_amdgcn_s_setprio(1); \
    _Pragma("unroll") \
    for (int nt=0;nt<4;++nt){ \
      o[nt] = __builtin_amdgcn_mfma_f32_32x32x16_bf16(pa0_.s, VF[nt*2+0], o[nt], 0,0,0); \
      o[nt] = __builtin_amdgcn_mfma_f32_32x32x16_bf16(pa1_.s, VF[nt*2+1], o[nt], 0,0,0); \
    } \
    __builtin_amdgcn_s_setprio(0); \
  }while(0)

    short8 kfA[8], kfB[8];
    LOADK(sb, kfA);
    for (int s0 = sb;; s0 += 64){
      {
        short8 vfA[8];
        LOADV(s0, vfA);                          // V first (older in vmcnt order)
        if (s0 + 32 <= se) LOADK(s0+32, kfB);    // K one tile ahead
        __builtin_amdgcn_sched_barrier(0);       // pin: loads issued before MFMAs
        COMPUTE(s0, kfA, vfA);
      }
      if (s0 + 32 > se) break;
      {
        short8 vfB[8];
        LOADV(s0+32, vfB);
        if (s0 + 64 <= se) LOADK(s0+64, kfA);
        __builtin_amdgcn_sched_barrier(0);
        COMPUTE(s0+32, kfB, vfB);
      }
      if (s0 + 64 > se) break;
    }
#undef LOADK
#undef LOADV
#undef COMPUTE
  }

  // partial den: per-lane scalar; q-row l&31 total = own + partner half.
  // hh waves compute identical den; only hh==0 stores. Unique writer per
  // (chunk,row,head) -> no atomics.
  if (hh == 0){
    float d = den_ + __shfl_xor(den_, 32, 64);
    if (lhi == 0)
      den_g[((size_t)chunk*4096 + tbase + lrow)*8 + head] = d;
  }

  // partial O: bf16 store to the chunk-private quarter (zeros if empty chunk).
  unsigned short* ob = o_parts + (size_t)chunk*4096*2048;
  #pragma unroll
  for (int nt=0;nt<4;++nt)
    #pragma unroll
    for (int r=0;r<16;++r){
      int row = (r&3)+8*(r>>2)+4*lhi;
      ob[(size_t)(tbase+row)*2048 + head*256 + hh*128 + nt*32 + lrow] = f2bf(o[nt][r]);
    }
}

// ---------------- partial-sum + den-normalize + group RMS + SiLU gate -------
__global__ __launch_bounds__(256) void k_rmsgate(const unsigned short* __restrict__ o_parts,
    const unsigned short* __restrict__ g_bf, const float* __restrict__ den_g,
    unsigned short* __restrict__ gated)
{
  int t = blockIdx.x;
  int tid = threadIdx.x;
  int head = tid >> 5;                       // 32 threads = one head group (256)
  float den = den_g[(size_t)t*8 + head]
            + den_g[(size_t)( 4096 + t)*8 + head]
            + den_g[(size_t)( 8192 + t)*8 + head]
            + den_g[(size_t)(12288 + t)*8 + head];
  float rs  = 1.0f/fminf(fmaxf(den, 1.0f), 50000.0f);
  size_t base = (size_t)t*2048 + tid*8;
  const size_t CS = (size_t)4096*2048;
  short8 a0 = *(const short8*)(o_parts + base);
  short8 a1 = *(const short8*)(o_parts + CS + base);
  short8 a2 = *(const short8*)(o_parts + 2*CS + base);
  short8 a3 = *(const short8*)(o_parts + 3*CS + base);
  short8 gv = *(const short8*)(g_bf + base);
  float of[8]; float ss = 0.f;
  #pragma unroll
  for (int j=0;j<8;++j){
    of[j] = (bf2f((unsigned short)a0[j]) + bf2f((unsigned short)a1[j])
           + bf2f((unsigned short)a2[j]) + bf2f((unsigned short)a3[j])) * rs;
    ss += of[j]*of[j];
  }
  #pragma unroll
  for (int off=1; off<32; off<<=1) ss += __shfl_xor(ss, off, 64);
  float rms = rsqrtf(ss*(1.0f/256.0f) + 1e-6f);
  short8 outv;
  #pragma unroll
  for (int j=0;j<8;++j){
    float g = bf2f((unsigned short)gv[j]);
    float si = g / (1.0f + expf(-g));
    outv[j] = (short)f2bf(si * of[j] * rms);
  }
  *(short8*)(gated + base) = outv;
}

// ---------------------------------------------------------------------------
extern "C" void kernel_launch(void* const* d_in, const int* in_sizes, int n_in,
                              void* d_out, int out_size, void* d_ws, size_t ws_size,
                              hipStream_t stream)
{
  const float* x    = (const float*)d_in[0];
  const float* sinp = (const float*)d_in[1];
  const float* cosp = (const float*)d_in[2];
  // d_in[3] = inner_mask: intentionally unused (computed analytically)
  const float* Wq = (const float*)d_in[4];
  const float* Wk = (const float*)d_in[5];
  const float* Wv = (const float*)d_in[6];
  const float* Wg = (const float*)d_in[7];
  const float* Wo = (const float*)d_in[8];

  char* ws = (char*)d_ws;
  size_t off = 0;
  auto alloc = [&](size_t bytes)->char*{ char* p = ws + off; off += (bytes + 255) & ~(size_t)255; return p; };
  unsigned short* x_bf   = (unsigned short*)alloc((size_t)4096*1024*2);  // reused as qr, then gated head
  unsigned short* WallT  = (unsigned short*)alloc((size_t)6144*1024*2);  // reused as krP, then gated tail
  float*          qk_f32 = (float*)         alloc((size_t)4096*2048*4);
  unsigned short* v_bf   = (unsigned short*)alloc((size_t)4096*2048*2);
  unsigned short* g_bf   = (unsigned short*)alloc((size_t)4096*2048*2);
  unsigned short* vP     = (unsigned short*)alloc((size_t)2048*4096*2);  // packed V fragments
  unsigned short* WoT    = (unsigned short*)alloc((size_t)1024*2048*2);
  unsigned short* o_parts= (unsigned short*)alloc((size_t)4*4096*2048*2); // 4 bf16 chunk partials
  float*          den_g  = (float*)         alloc((size_t)4*4096*8*4);
  unsigned short* qrp    = x_bf;                       // alias (x_bf dead after qkvg GEMM)
  unsigned short* krP    = WallT;                      // alias (WallT dead after qkvg GEMM)
  unsigned short* gated  = x_bf;                       // alias (qr/krP dead after k_attn)

  // prep: x->bf16 cvt + 5 fused weight transposes (one kernel)
  WPrepAll pa;
  pa.w[0] = { Wq, WallT,                        1024, 1024, 256 };
  pa.w[1] = { Wk, WallT + 1024*1024,            1024, 1024, 256 };
  pa.w[2] = { Wv, WallT + 2048*1024,            1024, 2048, 512 };
  pa.w[3] = { Wg, WallT + (size_t)4096*1024,    1024, 2048, 512 };
  pa.w[4] = { Wo, WoT,                          2048, 1024, 512 };
  k_prep<<<6144, 256, 0, stream>>>(x, x_bf, pa);

  // qkvg = x @ [Wq|Wk|Wv|Wg]
  k_gemm_bt<0><<<dim3(48,32,1), 256, 0, stream>>>(x_bf, WallT, 4096, 6144, 1024, qk_f32, v_bf, g_bf);

  // rotary (q->qrp row-major, k->krP fragment-major) + V transpose/pack
  k_rotpack<<<18432, 256, 0, stream>>>(qk_f32, sinp, cosp, qrp, krP, v_bf, vP);

  // retention attention -> 4 chunk-private bf16 partial O + fp32 partial den
  k_attn<<<2048, 256, 0, stream>>>(qrp, krP, vP, o_parts, den_g);

  // partial-sum + den-clip divide + RMS(group=256) + silu(g) gate -> gated
  k_rmsgate<<<4096, 256, 0, stream>>>(o_parts, g_bf, den_g, gated);

  // out = gated @ Wo -> d_out directly (single pass K=2048, one store per
  // element overwrites the 0xAA poison; no memset/atomics/addout needed)
  k_gemm_bt<1><<<dim3(8,32,1), 256, 0, stream>>>(gated, WoT, 4096, 1024, 2048,
                                                 (float*)d_out, nullptr, nullptr);

  (void)in_sizes; (void)n_in; (void)out_size; (void)ws_size;
}